// Round 5
// baseline (375.009 us; speedup 1.0000x reference)
//
#include <hip/hip_runtime.h>

// LGA3D ×3 (GANet local guided aggregation), fp32.
// out[c,d,h,w] = sum_{g,i,j} filt[g*25+i*5+j,h,w] * in[c,d+g-1,h+i-2,w+j-2]
//
// R2: async HBM->LDS DMA staging (global_load_lds). 125 -> 112 us/pass.
// R3 (REVERTED): 2 ch/block -> register cliff, occupancy 24%.
// R4: depth-unroll x4 + 8-plane LDS ring, 12 barriers. 112 -> ~105 us/pass.
//     BUT launch_bounds(256,4) forced filter spills (WRITE 98.3->106.5 MB).
// R5: cycle model says LDS-issue-bound (25 ds_read_b32/plane ~ 6960 cyc of the
//     ~7870-cyc interval). Three register-neutral changes:
//     (a) alignment-adaptive b64 loads: every lane does 2x ds_read_b64 + 1x
//         ds_read_b32 per row; even-parity lanes get taps (01)(23)(4), odd
//         lanes taps (12)(34)(0). Tap permutation compensated by per-lane
//         PERMUTED FILTER LOAD (free, done once). 25 -> 15 LDS instr/plane.
//     (b) group-packed FMA: groups 0,1 as one v_pk_fma_f32 chain (float2
//         f01[25] + float f2[25] = same 75 filter regs). 75 -> 50 FMA/plane.
//     (c) launch_bounds(256,3): stop spilling for an unreachable 4 waves/EU.

namespace {
constexpr int C  = 16, D = 48, H = 128, W = 256;
constexpr int TH = 4, TW = 64;
constexpr int LH = TH + 4;           // 8 tile rows (h0-2 .. h0+TH+1)
constexpr int LW = 72;               // 72 cols: gw = w0-4 .. w0+67 (16B aligned)
constexpr int HWp = H * W;
constexpr int CPLANE = LH * LW;      // 576 floats per plane tile
constexpr int SLOTS  = CPLANE / 4;   // 144 float4 staging slots
constexpr int NBUF   = 8;            // plane ring (18.4 KB LDS)
}

typedef float v2f __attribute__((ext_vector_type(2)));
static __device__ __forceinline__ v2f sp(float x) { return (v2f){x, x}; }

__global__ __launch_bounds__(256, 3)
void lga_pass(const float* __restrict__ in, const float* __restrict__ filt,
              float* __restrict__ out)
{
    __shared__ float buf[NBUF][CPLANE];

    const int tx = threadIdx.x;       // 0..63  (one wave per ty row)
    const int ty = threadIdx.y;       // 0..3
    const int tid = ty * 64 + tx;
    const int w0 = blockIdx.x * TW;
    const int h0 = blockIdx.y * TH;
    const int c  = blockIdx.z;
    const int h  = h0 + ty;
    const int w  = w0 + tx;
    const int rot = tx & 1;           // lane parity: tap rotation

    // ---- filters -> registers, permuted per lane parity ----
    // reg slot k of row i multiplies tap perm(k) = even? k : (k+1)%5.
    v2f  f01[25];                     // (group0, group1) packed
    float f2[25];                     // group2
    const int hw = h * W + w;
    #pragma unroll
    for (int i = 0; i < 5; ++i) {
        #pragma unroll
        for (int k = 0; k < 5; ++k) {
            const int pj  = (k + rot) % 5;          // k compile-time; cheap select
            const int idx = i * 5 + pj;
            f01[i * 5 + k] = (v2f){ filt[idx * HWp + hw], filt[(25 + idx) * HWp + hw] };
            f2 [i * 5 + k] = filt[(50 + idx) * HWp + hw];
        }
    }

    // ---- staging slot geometry (d-invariant) ----
    const bool haveSlot = tid < SLOTS;          // threads 144..255 idle in staging
    const int r  = tid / 18;                    // tile row 0..7
    const int q  = tid - r * 18;                // float4 index in row, 0..17
    const int gh = h0 - 2 + r;
    const int gw = w0 - 4 + 4 * q;              // 16B aligned; OOB all-or-nothing
    const bool valid = haveSlot && (gh >= 0) && (gh < H) && (gw >= 0) && (gw < W);
    const int planeOff = gh * W + gw;
    const float* planeBase = in + c * (D * HWp);

    // ---- pre-zero the ring: invalid slots must read 0 for all d ----
    for (int k = tid; k < NBUF * CPLANE; k += 256)
        (&buf[0][0])[k] = 0.f;
    __syncthreads();

    // async DMA: per-lane global addr, wave-uniform LDS base, lane stride 16B
    auto stage = [&](int dp) {
        if (valid && dp < D) {
            __builtin_amdgcn_global_load_lds(
                (const __attribute__((address_space(1))) void*)(planeBase + dp * HWp + planeOff),
                (__attribute__((address_space(3))) void*)(&buf[dp & (NBUF - 1)][ty * 256]),
                16, 0, 0);
        }
    };

    // rolling accumulators: a_prev = partial out[d-1], a_cur = partial out[d]
    float a_prev = 0.f, a_cur = 0.f;
    float* outp = out + c * (D * HWp) + h * W + w;

    // per-lane LDS read bases (dword indices within a plane):
    // tap0 dword = ty*LW + tx + 2 (+ i*LW); first b64 at +rot (even dword);
    // leftover b32 at tap 4 (even lanes) or tap 0 (odd lanes).
    const int sbase = ty * LW + tx + 2;
    const int pA    = sbase + rot;              // even dword -> 8B aligned
    const int pS    = sbase + (rot ? 0 : 4);    // the single b32 tap

    auto computePlane = [&](int d) {
        const float* pb  = &buf[d & (NBUF - 1)][0];
        const float* bp2 = pb + pA;             // b64 base (8B aligned)
        const float* bps = pb + pS;             // b32 base
        v2f  s01 = (v2f){0.f, 0.f};
        float s2v = 0.f;
        #pragma unroll
        for (int i = 0; i < 5; ++i) {
            const v2f  vab = *(const v2f*)(bp2 + i * LW);      // taps (0,1)|(1,2)
            const v2f  vcd = *(const v2f*)(bp2 + i * LW + 2);  // taps (2,3)|(3,4)
            const float ve = bps[i * LW];                      // tap  4 | 0
            s01 = __builtin_elementwise_fma(f01[i * 5 + 0], sp(vab.x), s01);
            s2v = fmaf(f2[i * 5 + 0], vab.x, s2v);
            s01 = __builtin_elementwise_fma(f01[i * 5 + 1], sp(vab.y), s01);
            s2v = fmaf(f2[i * 5 + 1], vab.y, s2v);
            s01 = __builtin_elementwise_fma(f01[i * 5 + 2], sp(vcd.x), s01);
            s2v = fmaf(f2[i * 5 + 2], vcd.x, s2v);
            s01 = __builtin_elementwise_fma(f01[i * 5 + 3], sp(vcd.y), s01);
            s2v = fmaf(f2[i * 5 + 3], vcd.y, s2v);
            s01 = __builtin_elementwise_fma(f01[i * 5 + 4], sp(ve), s01);
            s2v = fmaf(f2[i * 5 + 4], ve, s2v);
        }
        // s01.x = S0(d), s01.y = S1(d), s2v = S2(d)
        float done = a_prev + s2v;          // out[d-1] complete
        if (d > 0) outp[(d - 1) * HWp] = done;
        a_prev = a_cur + s01.y;
        a_cur  = s01.x;
    };

    // ---- prologue: planes 0..3 into ring slots 0..3 ----
    stage(0); stage(1); stage(2); stage(3);
    __syncthreads();   // compiler drains vmcnt(0) before barrier: planes resident

    // ---- main loop: 4 planes per interval, one barrier per interval ----
    for (int d0 = 0; d0 < D; d0 += 4) {
        stage(d0 + 4); stage(d0 + 5); stage(d0 + 6); stage(d0 + 7);  // in flight
        computePlane(d0);
        computePlane(d0 + 1);
        computePlane(d0 + 2);
        computePlane(d0 + 3);
        __syncthreads();   // vmcnt(0)+barrier: next 4 planes resident; ring safe
    }
    outp[(D - 1) * HWp] = a_prev;            // out[47] = S0(46)+S1(47)  (S2(48)=0)
}

extern "C" void kernel_launch(void* const* d_in, const int* in_sizes, int n_in,
                              void* d_out, int out_size, void* d_ws, size_t ws_size,
                              hipStream_t stream)
{
    const float* cost = (const float*)d_in[0];
    const float* filt = (const float*)d_in[1];
    float* out = (float*)d_out;

    // scratch for the middle pass: need one full cost-sized buffer
    const size_t needBytes = (size_t)C * D * HWp * sizeof(float);
    float* tmp = (ws_size >= needBytes) ? (float*)d_ws : (float*)d_in[0];
    // (fallback writes the input buffer; harness restores d_in before every timed launch)

    dim3 block(64, 4, 1);
    dim3 grid(W / TW, H / TH, C);   // 4 x 32 x 16 = 2048 blocks

    lga_pass<<<grid, block, 0, stream>>>(cost, filt, out);   // pass 1: cost -> out
    lga_pass<<<grid, block, 0, stream>>>(out,  filt, tmp);   // pass 2: out  -> tmp
    lga_pass<<<grid, block, 0, stream>>>(tmp,  filt, out);   // pass 3: tmp  -> out
}

// Round 6
// 353.242 us; speedup vs baseline: 1.0616x; 1.0616x over previous
//
#include <hip/hip_runtime.h>

// LGA3D ×3 (GANet local guided aggregation), fp32.
// out[c,d,h,w] = sum_{g,i,j} filt[g*25+i*5+j,h,w] * in[c,d+g-1,h+i-2,w+j-2]
//
// R2: async HBM->LDS DMA staging (global_load_lds). 125 -> 112 us/pass, occ 43%.
// R3 (REVERTED): 2 ch/block -> register cliff, occ 24%.
// R4: depth-unroll x4 + 8-plane LDS ring, 12 barriers/pass. ~105 us/pass but
//     launch_bounds(256,4) caused filter spills.
// R5: b64 parity reads + pk_fma. LDS instrs 25->15, VALU 75->50... time FLAT.
//     => neither VALU nor LDS issue is binding; latency/occupancy-bound.
// R6: consolidation + counted-vmcnt barrier (T4):
//     (a) minimal-register addressing back (single base, b32 reads; occ 43%
//         was the best operating point). Keep pk-packed filters (cheap, free).
//     (b) end-of-interval barrier = s_waitcnt vmcnt(3) + raw s_barrier:
//         guarantees the 4 staged planes landed (oldest outstanding VMEM)
//         while this interval's output stores float across the barrier.
//         Per-wave VMEM order pinned by sched_barrier(0) after the stages.

namespace {
constexpr int C  = 16, D = 48, H = 128, W = 256;
constexpr int TH = 4, TW = 64;
constexpr int LH = TH + 4;           // 8 tile rows (h0-2 .. h0+TH+1)
constexpr int LW = 72;               // 72 cols: gw = w0-4 .. w0+67 (16B aligned)
constexpr int HWp = H * W;
constexpr int CPLANE = LH * LW;      // 576 floats per plane tile
constexpr int SLOTS  = CPLANE / 4;   // 144 float4 staging slots
constexpr int NBUF   = 8;            // plane ring (18.4 KB LDS)
}

typedef float v2f __attribute__((ext_vector_type(2)));
static __device__ __forceinline__ v2f sp(float x) { return (v2f){x, x}; }

__global__ __launch_bounds__(256, 3)
void lga_pass(const float* __restrict__ in, const float* __restrict__ filt,
              float* __restrict__ out)
{
    __shared__ float buf[NBUF][CPLANE];

    const int tx = threadIdx.x;       // 0..63  (one wave per ty row)
    const int ty = threadIdx.y;       // 0..3
    const int tid = ty * 64 + tx;
    const int w0 = blockIdx.x * TW;
    const int h0 = blockIdx.y * TH;
    const int c  = blockIdx.z;
    const int h  = h0 + ty;
    const int w  = w0 + tx;

    // ---- filters -> registers: (g0,g1) packed for v_pk_fma, g2 scalar ----
    v2f  f01[25];
    float f2[25];
    const int hw = h * W + w;
    #pragma unroll
    for (int k = 0; k < 25; ++k) {
        f01[k] = (v2f){ filt[k * HWp + hw], filt[(25 + k) * HWp + hw] };
        f2 [k] = filt[(50 + k) * HWp + hw];
    }

    // ---- staging slot geometry (d-invariant) ----
    const bool haveSlot = tid < SLOTS;          // threads 144..255 idle in staging
    const int r  = tid / 18;                    // tile row 0..7
    const int q  = tid - r * 18;                // float4 index in row, 0..17
    const int gh = h0 - 2 + r;
    const int gw = w0 - 4 + 4 * q;              // 16B aligned; OOB all-or-nothing
    const bool valid = haveSlot && (gh >= 0) && (gh < H) && (gw >= 0) && (gw < W);
    const int planeOff = gh * W + gw;
    const float* planeBase = in + c * (D * HWp);

    // ---- pre-zero the ring: invalid slots must read 0 for all d ----
    for (int k = tid; k < NBUF * CPLANE; k += 256)
        (&buf[0][0])[k] = 0.f;
    __syncthreads();

    // async DMA: per-lane global addr, wave-uniform LDS base, lane stride 16B
    auto stage = [&](int dp) {
        if (valid && dp < D) {
            __builtin_amdgcn_global_load_lds(
                (const __attribute__((address_space(1))) void*)(planeBase + dp * HWp + planeOff),
                (__attribute__((address_space(3))) void*)(&buf[dp & (NBUF - 1)][ty * 256]),
                16, 0, 0);
        }
    };

    // rolling accumulators: a_prev = partial out[d-1], a_cur = partial out[d]
    float a_prev = 0.f, a_cur = 0.f;
    float* outp = out + c * (D * HWp) + h * W + w;

    auto computePlane = [&](int d) {
        // patch base: buffer row ty = input row h-2; col tx+2 is gw = w-2
        const float* bp = &buf[d & (NBUF - 1)][ty * LW + tx + 2];
        v2f  s01 = (v2f){0.f, 0.f};
        float s2v = 0.f;
        #pragma unroll
        for (int i = 0; i < 5; ++i) {
            #pragma unroll
            for (int j = 0; j < 5; ++j) {
                const float v = bp[i * LW + j];
                s01 = __builtin_elementwise_fma(f01[i * 5 + j], sp(v), s01);
                s2v = fmaf(f2[i * 5 + j], v, s2v);
            }
        }
        // s01.x = S0(d), s01.y = S1(d), s2v = S2(d)
        if (d > 0) outp[(d - 1) * HWp] = a_prev + s2v;   // out[d-1] complete
        a_prev = a_cur + s01.y;
        a_cur  = s01.x;
    };

    // ---- prologue: planes 0..3 into ring slots 0..3 ----
    stage(0); stage(1); stage(2); stage(3);
    __syncthreads();   // full drain once: planes 0..3 resident

    // ---- main loop: 4 planes per interval, counted-vmcnt barrier ----
    for (int d0 = 0; d0 < D; d0 += 4) {
        stage(d0 + 4); stage(d0 + 5); stage(d0 + 6); stage(d0 + 7);  // in flight
        __builtin_amdgcn_sched_barrier(0);   // pin VMEM order: stages before stores
        computePlane(d0);
        computePlane(d0 + 1);
        computePlane(d0 + 2);
        computePlane(d0 + 3);
        // Per-wave VMEM order this interval: [4 stage DMAs][<=4 stores].
        // vmcnt(3): all 4 stages (oldest) complete; newest <=3 stores float
        // across the barrier. Ring halves are disjoint (read d0..d0+3, write
        // d0+4..d0+7); barrier orders interval n reads vs n+1 DMA writes.
        asm volatile("s_waitcnt vmcnt(3)" ::: "memory");
        __builtin_amdgcn_s_barrier();
    }
    outp[(D - 1) * HWp] = a_prev;            // out[47] = S0(46)+S1(47)  (S2(48)=0)
}

extern "C" void kernel_launch(void* const* d_in, const int* in_sizes, int n_in,
                              void* d_out, int out_size, void* d_ws, size_t ws_size,
                              hipStream_t stream)
{
    const float* cost = (const float*)d_in[0];
    const float* filt = (const float*)d_in[1];
    float* out = (float*)d_out;

    // scratch for the middle pass: need one full cost-sized buffer
    const size_t needBytes = (size_t)C * D * HWp * sizeof(float);
    float* tmp = (ws_size >= needBytes) ? (float*)d_ws : (float*)d_in[0];
    // (fallback writes the input buffer; harness restores d_in before every timed launch)

    dim3 block(64, 4, 1);
    dim3 grid(W / TW, H / TH, C);   // 4 x 32 x 16 = 2048 blocks

    lga_pass<<<grid, block, 0, stream>>>(cost, filt, out);   // pass 1: cost -> out
    lga_pass<<<grid, block, 0, stream>>>(out,  filt, tmp);   // pass 2: out  -> tmp
    lga_pass<<<grid, block, 0, stream>>>(tmp,  filt, out);   // pass 3: tmp  -> out
}